// Round 1
// baseline (9097.820 us; speedup 1.0000x reference)
//
#include <hip/hip_runtime.h>

// NeuralODE RK4 integrator, fp32 VALU baseline.
// BS=1024, ZDIM=HID=256, TLEN=128 (127 RK4 steps, 508 f-evals).
// One WG of 256 threads handles RPW=4 batch rows; thread j owns output
// column j. z/zin/h staged in LDS; weights streamed from global (L2-resident).

#define BS   1024
#define ZDIM 256
#define HID  256
#define TLEN 128
#define RPW  4          // rows per workgroup -> 256 workgroups

__global__ __launch_bounds__(256, 1)
void ode_rk4_kernel(const float* __restrict__ z0,
                    const float* __restrict__ t,
                    const float* __restrict__ W1,
                    const float* __restrict__ b1,
                    const float* __restrict__ W2,
                    const float* __restrict__ b2,
                    float* __restrict__ out)
{
    __shared__ float zin[RPW][ZDIM];   // current input to f
    __shared__ float hbuf[RPW][HID];   // tanh(z@W1+b1)

    const int j = threadIdx.x;               // column 0..255
    const int rowbase = blockIdx.x * RPW;    // 4 rows per block

    const float b1j = b1[j];
    const float b2j = b2[j];

    float zloc[RPW];   // z at step start, column j
    float kacc[RPW];   // k1 + 2k2 + 2k3 (+k4) accumulator
    float fout[RPW];   // f(zin), column j

    #pragma unroll
    for (int r = 0; r < RPW; ++r) {
        zloc[r] = z0[(rowbase + r) * ZDIM + j];
        zin[r][j] = zloc[r];
    }
    __syncthreads();

    for (int step = 0; step < TLEN - 1; ++step) {
        const float t0 = t[step];
        const float t1 = t[step + 1];
        const float hstep = t1 - t0;

        #pragma unroll 1
        for (int stage = 0; stage < 4; ++stage) {
            // ---- stage 1: s = zin @ W1 + b1  (reads zin, writes hbuf) ----
            float s0 = b1j, s1 = b1j, s2 = b1j, s3 = b1j;
            #pragma unroll 4
            for (int k4 = 0; k4 < ZDIM; k4 += 4) {
                const float4 a0 = *(const float4*)&zin[0][k4];
                const float4 a1 = *(const float4*)&zin[1][k4];
                const float4 a2 = *(const float4*)&zin[2][k4];
                const float4 a3 = *(const float4*)&zin[3][k4];
                const float w0 = W1[(k4 + 0) * HID + j];
                const float w1 = W1[(k4 + 1) * HID + j];
                const float w2 = W1[(k4 + 2) * HID + j];
                const float w3 = W1[(k4 + 3) * HID + j];
                s0 += a0.x * w0 + a0.y * w1 + a0.z * w2 + a0.w * w3;
                s1 += a1.x * w0 + a1.y * w1 + a1.z * w2 + a1.w * w3;
                s2 += a2.x * w0 + a2.y * w1 + a2.z * w2 + a2.w * w3;
                s3 += a3.x * w0 + a3.y * w1 + a3.z * w2 + a3.w * w3;
            }
            hbuf[0][j] = tanhf(s0);
            hbuf[1][j] = tanhf(s1);
            hbuf[2][j] = tanhf(s2);
            hbuf[3][j] = tanhf(s3);
            __syncthreads();   // hbuf ready; all zin reads complete

            // ---- stage 2: fout = hbuf @ W2 + b2 (reads hbuf) ----
            float o0 = b2j, o1 = b2j, o2 = b2j, o3 = b2j;
            #pragma unroll 4
            for (int k4 = 0; k4 < HID; k4 += 4) {
                const float4 a0 = *(const float4*)&hbuf[0][k4];
                const float4 a1 = *(const float4*)&hbuf[1][k4];
                const float4 a2 = *(const float4*)&hbuf[2][k4];
                const float4 a3 = *(const float4*)&hbuf[3][k4];
                const float w0 = W2[(k4 + 0) * ZDIM + j];
                const float w1 = W2[(k4 + 1) * ZDIM + j];
                const float w2 = W2[(k4 + 2) * ZDIM + j];
                const float w3 = W2[(k4 + 3) * ZDIM + j];
                o0 += a0.x * w0 + a0.y * w1 + a0.z * w2 + a0.w * w3;
                o1 += a1.x * w0 + a1.y * w1 + a1.z * w2 + a1.w * w3;
                o2 += a2.x * w0 + a2.y * w1 + a2.z * w2 + a2.w * w3;
                o3 += a3.x * w0 + a3.y * w1 + a3.z * w2 + a3.w * w3;
            }
            fout[0] = o0; fout[1] = o1; fout[2] = o2; fout[3] = o3;

            // ---- RK4 epilogue: update kacc, write next zin (column j) ----
            #pragma unroll
            for (int r = 0; r < RPW; ++r) {
                if (stage == 0) {
                    kacc[r] = fout[r];
                    zin[r][j] = zloc[r] + 0.5f * hstep * fout[r];
                } else if (stage == 1) {
                    kacc[r] += 2.0f * fout[r];
                    zin[r][j] = zloc[r] + 0.5f * hstep * fout[r];
                } else if (stage == 2) {
                    kacc[r] += 2.0f * fout[r];
                    zin[r][j] = zloc[r] + hstep * fout[r];
                } else {
                    kacc[r] += fout[r];
                    zloc[r] += (hstep * (1.0f / 6.0f)) * kacc[r];
                    zin[r][j] = zloc[r];
                }
            }
            __syncthreads();   // zin ready for next stage; hbuf reads done
        }
    }

    #pragma unroll
    for (int r = 0; r < RPW; ++r)
        out[(rowbase + r) * ZDIM + j] = zloc[r];
}

extern "C" void kernel_launch(void* const* d_in, const int* in_sizes, int n_in,
                              void* d_out, int out_size, void* d_ws, size_t ws_size,
                              hipStream_t stream) {
    const float* z0 = (const float*)d_in[0];
    const float* t  = (const float*)d_in[1];
    const float* W1 = (const float*)d_in[2];
    const float* b1 = (const float*)d_in[3];
    const float* W2 = (const float*)d_in[4];
    const float* b2 = (const float*)d_in[5];
    float* out = (float*)d_out;

    dim3 grid(BS / RPW);   // 256 workgroups
    dim3 block(256);
    hipLaunchKernelGGL(ode_rk4_kernel, grid, block, 0, stream,
                       z0, t, W1, b1, W2, b2, out);
}

// Round 2
// 1013.486 us; speedup vs baseline: 8.9768x; 8.9768x over previous
//
#include <hip/hip_runtime.h>
#include <hip/hip_bf16.h>

// NeuralODE RK4, bf16 MFMA persistent kernel.
// BS=1024, ZDIM=HID=256, TLEN=128 -> 127 steps x 4 stages = 508 f-evals.
// 64 WGs x 256 threads (4 waves). Each WG owns 16 batch rows; wave w owns
// output columns [64w, 64w+64) (4 n-tiles of 16). Weights live in VGPRs in
// MFMA B-frag layout (loaded once). State (16x256) round-trips through LDS
// in MFMA A-frag layout between the two GEMMs / stages. z kept fp32 in
// registers (C-layout); only GEMM inputs are bf16.

#define BS   1024
#define ZDIM 256
#define HID  256
#define TLEN 128

typedef short v8s __attribute__((ext_vector_type(8)));
typedef float v4f __attribute__((ext_vector_type(4)));

static __device__ __forceinline__ ushort f2bf(float x) {
    union { float f; unsigned u; } v; v.f = x;
    unsigned r = v.u + 0x7FFFu + ((v.u >> 16) & 1u);   // RNE
    return (ushort)(r >> 16);
}

static __device__ __forceinline__ float fast_tanh(float x) {
    // tanh(x) = 1 - 2/(e^{2x}+1); saturates correctly for large |x|
    float e = __expf(2.0f * x);
    return 1.0f - 2.0f / (e + 1.0f);
}

__global__ __launch_bounds__(256, 1)
void ode_mfma_kernel(const float* __restrict__ z0,
                     const float* __restrict__ t,
                     const float* __restrict__ W1,
                     const float* __restrict__ b1,
                     const float* __restrict__ W2,
                     const float* __restrict__ b2,
                     float* __restrict__ out)
{
    // A-frag layout buffers: [ks][chunk=m+16q][j], u16 units, 4096 each
    __shared__ ushort zbuf[8 * 64 * 8];
    __shared__ ushort hbuf[8 * 64 * 8];

    const int tid  = threadIdx.x;
    const int wv   = tid >> 6;      // wave 0..3
    const int lane = tid & 63;
    const int q    = lane >> 4;     // quad 0..3
    const int ln   = lane & 15;
    const int rowbase = blockIdx.x * 16;
    const int mbase   = q * 4;      // C-layout rows 4q..4q+3

    // ---- one-time: weights -> registers in B-frag layout ----
    // B-frag(nt, ks): lane holds W[k = 32ks + 8q + j][c = 64wv + 16nt + ln]
    v8s w1f[4][8], w2f[4][8];
    #pragma unroll
    for (int nt = 0; nt < 4; ++nt) {
        const int c = wv * 64 + nt * 16 + ln;
        #pragma unroll
        for (int ks = 0; ks < 8; ++ks) {
            v8s a, b;
            #pragma unroll
            for (int j = 0; j < 8; ++j) {
                const int k = ks * 32 + q * 8 + j;
                a[j] = (short)f2bf(W1[k * HID  + c]);
                b[j] = (short)f2bf(W2[k * ZDIM + c]);
            }
            w1f[nt][ks] = a;
            w2f[nt][ks] = b;
        }
    }

    float b1v[4], b2v[4];
    #pragma unroll
    for (int nt = 0; nt < 4; ++nt) {
        b1v[nt] = b1[wv * 64 + nt * 16 + ln];
        b2v[nt] = b2[wv * 64 + nt * 16 + ln];
    }

    // store offset (u16 units) for C-layout value (m, c):
    // idx = (c>>5)*512 + (m + 16*((c&31)>>3))*8 + (c&7)
    int woff[4];
    #pragma unroll
    for (int nt = 0; nt < 4; ++nt) {
        const int c = wv * 64 + nt * 16 + ln;
        woff[nt] = (c >> 5) * 512 + ((c & 31) >> 3) * 128 + (c & 7);
    }

    // ---- initial state: zloc fp32 (C-layout), zbuf bf16 (A-frag layout) ----
    float zloc[4][4];
    #pragma unroll
    for (int nt = 0; nt < 4; ++nt) {
        const int c = wv * 64 + nt * 16 + ln;
        #pragma unroll
        for (int r = 0; r < 4; ++r) {
            const float zv = z0[(rowbase + mbase + r) * ZDIM + c];
            zloc[nt][r] = zv;
            zbuf[woff[nt] + (mbase + r) * 8] = f2bf(zv);
        }
    }
    __syncthreads();

    float kacc[4][4];

    #pragma unroll 1
    for (int step = 0; step < TLEN - 1; ++step) {
        const float t0 = t[step];
        const float h  = t[step + 1] - t0;

        #pragma unroll
        for (int stage = 0; stage < 4; ++stage) {
            // ---- GEMM1: s = zin @ W1 + b1 ----
            v4f acc[4];
            #pragma unroll
            for (int nt = 0; nt < 4; ++nt)
                acc[nt] = (v4f){b1v[nt], b1v[nt], b1v[nt], b1v[nt]};
            #pragma unroll
            for (int ks = 0; ks < 8; ++ks) {
                const v8s afrag = *(const v8s*)&zbuf[ks * 512 + lane * 8];
                #pragma unroll
                for (int nt = 0; nt < 4; ++nt)
                    acc[nt] = __builtin_amdgcn_mfma_f32_16x16x32_bf16(
                        afrag, w1f[nt][ks], acc[nt], 0, 0, 0);
            }
            // tanh -> hbuf (A-frag layout)
            #pragma unroll
            for (int nt = 0; nt < 4; ++nt)
                #pragma unroll
                for (int r = 0; r < 4; ++r)
                    hbuf[woff[nt] + (mbase + r) * 8] = f2bf(fast_tanh(acc[nt][r]));
            __syncthreads();

            // ---- GEMM2: f = h @ W2 + b2 ----
            v4f acc2[4];
            #pragma unroll
            for (int nt = 0; nt < 4; ++nt)
                acc2[nt] = (v4f){b2v[nt], b2v[nt], b2v[nt], b2v[nt]};
            #pragma unroll
            for (int ks = 0; ks < 8; ++ks) {
                const v8s afrag = *(const v8s*)&hbuf[ks * 512 + lane * 8];
                #pragma unroll
                for (int nt = 0; nt < 4; ++nt)
                    acc2[nt] = __builtin_amdgcn_mfma_f32_16x16x32_bf16(
                        afrag, w2f[nt][ks], acc2[nt], 0, 0, 0);
            }

            // ---- RK4 epilogue: update kacc/zloc, write next zin ----
            #pragma unroll
            for (int nt = 0; nt < 4; ++nt) {
                #pragma unroll
                for (int r = 0; r < 4; ++r) {
                    const float f = acc2[nt][r];
                    float znext;
                    if (stage == 0) {
                        kacc[nt][r] = f;
                        znext = zloc[nt][r] + 0.5f * h * f;
                    } else if (stage == 1) {
                        kacc[nt][r] += 2.0f * f;
                        znext = zloc[nt][r] + 0.5f * h * f;
                    } else if (stage == 2) {
                        kacc[nt][r] += 2.0f * f;
                        znext = zloc[nt][r] + h * f;
                    } else {
                        kacc[nt][r] += f;
                        zloc[nt][r] += (h * (1.0f / 6.0f)) * kacc[nt][r];
                        znext = zloc[nt][r];
                    }
                    zbuf[woff[nt] + (mbase + r) * 8] = f2bf(znext);
                }
            }
            __syncthreads();
        }
    }

    // ---- store final z (fp32) ----
    #pragma unroll
    for (int nt = 0; nt < 4; ++nt) {
        const int c = wv * 64 + nt * 16 + ln;
        #pragma unroll
        for (int r = 0; r < 4; ++r)
            out[(rowbase + mbase + r) * ZDIM + c] = zloc[nt][r];
    }
}

extern "C" void kernel_launch(void* const* d_in, const int* in_sizes, int n_in,
                              void* d_out, int out_size, void* d_ws, size_t ws_size,
                              hipStream_t stream) {
    const float* z0 = (const float*)d_in[0];
    const float* t  = (const float*)d_in[1];
    const float* W1 = (const float*)d_in[2];
    const float* b1 = (const float*)d_in[3];
    const float* W2 = (const float*)d_in[4];
    const float* b2 = (const float*)d_in[5];
    float* out = (float*)d_out;

    dim3 grid(BS / 16);    // 64 workgroups, 16 batch rows each
    dim3 block(256);       // 4 waves
    hipLaunchKernelGGL(ode_mfma_kernel, grid, block, 0, stream,
                       z0, t, W1, b1, W2, b2, out);
}

// Round 3
// 532.872 us; speedup vs baseline: 17.0732x; 1.9019x over previous
//
#include <hip/hip_runtime.h>
#include <hip/hip_bf16.h>

// NeuralODE RK4, bf16 MFMA persistent kernel, swapped-operand layout.
// BS=1024, ZDIM=HID=256, TLEN=128 -> 127 steps x 4 stages = 508 f-evals.
//
// 64 WGs x 512 threads (8 waves, 2/SIMD). WG owns 16 batch rows; wave wv owns
// output cols [32wv, 32wv+32) (2 n-tiles). Weights in VGPRs in B-frag layout.
//
// Swapped trick: S = z@W computed as S^T = W^T @ z^T by passing the weight
// frag as the MFMA A-operand and the state frag as the B-operand. The C/D
// layout then has col(lane&15) = batch row m, row(quad*4+r) = output col c.
// Consequence: the state value a lane produces has the SAME m as the frags it
// must load next -> LDS round-trip is per-m contiguous: packed b64 writes,
// b128 frag reads, zero bank conflicts with row stride 264 u16.

#define BS   1024
#define ZDIM 256
#define TLEN 128
#define ROWSTRIDE 264   // u16 units; 528 B = 16B-aligned, odd multiple of 4 units

typedef short v8s __attribute__((ext_vector_type(8)));
typedef float v4f __attribute__((ext_vector_type(4)));

static __device__ __forceinline__ ushort f2bf_rne(float x) {
    union { float f; unsigned u; } v; v.f = x;
    unsigned r = v.u + 0x7FFFu + ((v.u >> 16) & 1u);
    return (ushort)(r >> 16);
}

static __device__ __forceinline__ unsigned pk2(float a, float b) {
    union { __hip_bfloat162 h; unsigned u; } cv;
    cv.h = __float22bfloat162_rn(make_float2(a, b));
    return cv.u;
}

static __device__ __forceinline__ float fast_tanh(float x) {
    // tanh(x) = 1 - 2/(exp2(2x*log2e)+1); v_exp + v_rcp, no slow libm div
    float e = __builtin_amdgcn_exp2f(2.88539008177793f * x);
    float r = __builtin_amdgcn_rcpf(e + 1.0f);
    return 1.0f - 2.0f * r;
}

__global__ __launch_bounds__(512, 1)
void ode_mfma_kernel(const float* __restrict__ z0,
                     const float* __restrict__ t,
                     const float* __restrict__ W1,
                     const float* __restrict__ b1,
                     const float* __restrict__ W2,
                     const float* __restrict__ b2,
                     float* __restrict__ out)
{
    // state buffers, swapped layout: buf[m][c] bf16, row stride ROWSTRIDE
    __shared__ ushort zbuf[16 * ROWSTRIDE];
    __shared__ ushort hbuf[16 * ROWSTRIDE];

    const int tid  = threadIdx.x;
    const int wv   = tid >> 6;        // 0..7
    const int lane = tid & 63;
    const int q    = lane >> 4;       // 0..3
    const int ln   = lane & 15;       // = batch row m (within tile)
    const int rowbase = blockIdx.x * 16;

    // ---- one-time: weights -> registers, B-frag layout ----
    // frag[ct][ks]: lane holds W[k = 32ks + 8q + j][c = 32wv + 16ct + ln]
    v8s w1f[2][8], w2f[2][8];
    #pragma unroll
    for (int ct = 0; ct < 2; ++ct) {
        const int c = wv * 32 + ct * 16 + ln;
        #pragma unroll
        for (int ks = 0; ks < 8; ++ks) {
            v8s a, b;
            #pragma unroll
            for (int j = 0; j < 8; ++j) {
                const int k = ks * 32 + q * 8 + j;
                a[j] = (short)f2bf_rne(W1[k * ZDIM + c]);
                b[j] = (short)f2bf_rne(W2[k * ZDIM + c]);
            }
            w1f[ct][ks] = a;
            w2f[ct][ks] = b;
        }
    }

    // biases in C'-layout: value row (c = 32wv + 16ct + 4q + r)
    v4f b1f[2], b2f[2];
    #pragma unroll
    for (int ct = 0; ct < 2; ++ct)
        #pragma unroll
        for (int r = 0; r < 4; ++r) {
            b1f[ct][r] = b1[wv * 32 + ct * 16 + q * 4 + r];
            b2f[ct][r] = b2[wv * 32 + ct * 16 + q * 4 + r];
        }

    // LDS offsets (u16 units)
    const int rdbase = ln * ROWSTRIDE + q * 8;            // + 32*ks, b128 reads
    const int wrbase = ln * ROWSTRIDE + wv * 32 + q * 4;  // + 16*ct,  b64 writes

    // ---- initial state ----
    float zloc[2][4];   // z[m=ln][c = 32wv+16ct+4q+r], fp32
    #pragma unroll
    for (int ct = 0; ct < 2; ++ct) {
        #pragma unroll
        for (int r = 0; r < 4; ++r)
            zloc[ct][r] = z0[(rowbase + ln) * ZDIM + wv * 32 + ct * 16 + q * 4 + r];
        uint2 p; p.x = pk2(zloc[ct][0], zloc[ct][1]); p.y = pk2(zloc[ct][2], zloc[ct][3]);
        *(uint2*)&zbuf[wrbase + ct * 16] = p;
    }
    __syncthreads();

    float kacc[2][4];

    #pragma unroll 1
    for (int step = 0; step < TLEN - 1; ++step) {
        const float h = t[step + 1] - t[step];

        #pragma unroll
        for (int stage = 0; stage < 4; ++stage) {
            // ---- GEMM1: S^T = W1^T z^T + b1 ----
            v4f acc0 = b1f[0], acc1 = b1f[1];
            #pragma unroll
            for (int ks = 0; ks < 8; ++ks) {
                const v8s zf = *(const v8s*)&zbuf[rdbase + ks * 32];
                acc0 = __builtin_amdgcn_mfma_f32_16x16x32_bf16(w1f[0][ks], zf, acc0, 0, 0, 0);
                acc1 = __builtin_amdgcn_mfma_f32_16x16x32_bf16(w1f[1][ks], zf, acc1, 0, 0, 0);
            }
            // tanh -> hbuf (packed b64 per ct)
            {
                uint2 p0, p1;
                p0.x = pk2(fast_tanh(acc0[0]), fast_tanh(acc0[1]));
                p0.y = pk2(fast_tanh(acc0[2]), fast_tanh(acc0[3]));
                p1.x = pk2(fast_tanh(acc1[0]), fast_tanh(acc1[1]));
                p1.y = pk2(fast_tanh(acc1[2]), fast_tanh(acc1[3]));
                *(uint2*)&hbuf[wrbase]      = p0;
                *(uint2*)&hbuf[wrbase + 16] = p1;
            }
            __syncthreads();

            // ---- GEMM2: f^T = W2^T h^T + b2 ----
            v4f f0 = b2f[0], f1 = b2f[1];
            #pragma unroll
            for (int ks = 0; ks < 8; ++ks) {
                const v8s hf = *(const v8s*)&hbuf[rdbase + ks * 32];
                f0 = __builtin_amdgcn_mfma_f32_16x16x32_bf16(w2f[0][ks], hf, f0, 0, 0, 0);
                f1 = __builtin_amdgcn_mfma_f32_16x16x32_bf16(w2f[1][ks], hf, f1, 0, 0, 0);
            }

            // ---- RK4 epilogue ----
            #pragma unroll
            for (int ct = 0; ct < 2; ++ct) {
                float zn[4];
                #pragma unroll
                for (int r = 0; r < 4; ++r) {
                    const float f = (ct == 0) ? f0[r] : f1[r];
                    if (stage == 0) {
                        kacc[ct][r] = f;
                        zn[r] = zloc[ct][r] + 0.5f * h * f;
                    } else if (stage == 1) {
                        kacc[ct][r] += 2.0f * f;
                        zn[r] = zloc[ct][r] + 0.5f * h * f;
                    } else if (stage == 2) {
                        kacc[ct][r] += 2.0f * f;
                        zn[r] = zloc[ct][r] + h * f;
                    } else {
                        kacc[ct][r] += f;
                        zloc[ct][r] += (h * (1.0f / 6.0f)) * kacc[ct][r];
                        zn[r] = zloc[ct][r];
                    }
                }
                uint2 p; p.x = pk2(zn[0], zn[1]); p.y = pk2(zn[2], zn[3]);
                *(uint2*)&zbuf[wrbase + ct * 16] = p;
            }
            __syncthreads();
        }
    }

    // ---- final store (one-time, uncoalesced is fine) ----
    #pragma unroll
    for (int ct = 0; ct < 2; ++ct)
        #pragma unroll
        for (int r = 0; r < 4; ++r)
            out[(rowbase + ln) * ZDIM + wv * 32 + ct * 16 + q * 4 + r] = zloc[ct][r];
}

extern "C" void kernel_launch(void* const* d_in, const int* in_sizes, int n_in,
                              void* d_out, int out_size, void* d_ws, size_t ws_size,
                              hipStream_t stream) {
    const float* z0 = (const float*)d_in[0];
    const float* t  = (const float*)d_in[1];
    const float* W1 = (const float*)d_in[2];
    const float* b1 = (const float*)d_in[3];
    const float* W2 = (const float*)d_in[4];
    const float* b2 = (const float*)d_in[5];
    float* out = (float*)d_out;

    dim3 grid(BS / 16);    // 64 workgroups, 16 batch rows each
    dim3 block(512);       // 8 waves, 2 per SIMD
    hipLaunchKernelGGL(ode_mfma_kernel, grid, block, 0, stream,
                       z0, t, W1, b1, W2, b2, out);
}